// Round 25
// baseline (42.834 us; speedup 1.0000x reference)
//
#include <hip/hip_runtime.h>
#include <math.h>

// TopKGate: logits = x @ W^T ; softmax ; top-2 ; scatter weights + indices(float).
// x: [8192,4096] f32, W: [64,4096] f32.
// d_out (f32 flat): weights [8192*64] then indices [8192*2] as floats.
//
// MFMA path: f32 as bf16 hi/lo split, 3 passes (hh+lh+hl; ll ~2^-16 dropped).
// Round-25 = Round-24 (40.9us best) + B PING-PONG within the 128-VGPR cap:
// dsB for chunk c+1 issues one full phase (~400cy) before its MFMA consumes
// it, so the per-phase exposed LDS latency (~50-100cy after cvt cover)
// vanishes; compiler emits counted lgkmcnt so current MFMA doesn't wait on
// the new reads. Paid for by x-ring 4->3 (still ~1200cy cover vs ~900 HBM).
// Budget: bA+bB 64 + ring 24 + acc 16 + ah/al 8 + addr ~ 127 <= 128.
// Geometry/prep/partials/finalize identical to R24.

#define TOKENS 8192
#define DIM    4096
#define NEXP   64

#define KS     8                             // k-split across blocks
#define KSEG   (DIM / KS)                    // 512 k per block
#define NCHB   (KSEG / 32)                   // 16 chunks per block
#define PNK    256                           // k per panel stage
#define NCHP   (PNK / 32)                    // 8 chunks per stage

#define SBAR() __builtin_amdgcn_sched_barrier(0)

typedef __attribute__((ext_vector_type(8))) short  short8;
typedef __attribute__((ext_vector_type(4))) float  f32x4;
typedef __attribute__((ext_vector_type(8))) float  f32x8;

__device__ __forceinline__ void bf16split(float v, short& hi, short& lo) {
    unsigned u = __float_as_uint(v);
    hi = (short)(u >> 16);
    float r = v - __uint_as_float(u & 0xffff0000u);
    lo = (short)(__float_as_uint(r) >> 16);
}

// ---- main: 128 tokens/block (8 waves x 16), 2-stage 64 KB B panel ----
__global__ __launch_bounds__(512, 4)
void tg_mfma(const float* __restrict__ x, const float* __restrict__ W,
             float* __restrict__ part) {
    // B panel: [hi/lo][chunk][nt][lane] short8 = 64 KB
    __shared__ short8 Bls[2][NCHP][4][64];

    const int tid  = threadIdx.x;
    const int lane = tid & 63;
    const int wave = tid >> 6;                   // token sub-group 0..7
    const int tg   = blockIdx.x >> 3;            // token group 0..63
    const int ks   = blockIdx.x & 7;             // k split 0..7
    const int t0   = tg * 128 + wave * 16;
    const int row  = lane & 15;                  // A row (token) / D col tag
    const int grp  = lane >> 4;

    const float* xp = x + (size_t)(t0 + row) * DIM + ks * KSEG + grp * 8;
    auto ldx = [&](int c) {                      // c = global chunk 0..15
        return *reinterpret_cast<const f32x8*>(xp + c * 32);
    };

    // issue the x ring FIRST so it's deep in flight during stage-0 prep
    f32x8 x0 = ldx(0), x1 = ldx(1), x2 = ldx(2);

    // ---- B prep for one stage (validated mapping), 4 slots/thread ----
    auto prep = [&](int stage) {
        const int k0 = ks * KSEG + stage * PNK;
#pragma unroll
        for (int s4 = 0; s4 < 4; ++s4) {
            const int s   = s4 * 512 + tid;      // 0..2047
            const int c   = s >> 8;              // 0..7
            const int rem = s & 255;
            const int nt  = rem >> 6;
            const int ln  = rem & 63;
            const int e   = nt * 16 + (ln & 15);
            const int kb  = k0 + c * 32 + (ln >> 4) * 8;
            const f32x8 wv = *reinterpret_cast<const f32x8*>(W + (size_t)e * DIM + kb);
            short8 h, l;
#pragma unroll
            for (int j = 0; j < 8; ++j) {
                short hh, ll;
                bf16split(wv[j], hh, ll);
                h[j] = hh; l[j] = ll;
            }
            Bls[0][c][nt][ln] = h;
            Bls[1][c][nt][ln] = l;
        }
    };

    f32x4 acc[4];
#pragma unroll
    for (int nt = 0; nt < 4; ++nt) acc[nt] = (f32x4){0.f, 0.f, 0.f, 0.f};

    short8 bA[8], bB[8];
    auto dsB = [&](short8 (&b)[8], int c) {      // 8 x ds_read_b128, conflict-free
#pragma unroll
        for (int nt = 0; nt < 4; ++nt) {
            b[nt]     = Bls[0][c][nt][lane];
            b[4 + nt] = Bls[1][c][nt][lane];
        }
    };
    auto cvt = [&](const f32x8& xv, short8& ah, short8& al) {
#pragma unroll
        for (int j = 0; j < 8; ++j) {
            short hh, ll;
            bf16split(xv[j], hh, ll);
            ah[j] = hh; al[j] = ll;
        }
    };
    auto mfma12 = [&](const short8& ah, const short8& al, const short8 (&b)[8]) {
        // 3-pass split: hh + lh + hl (ll ~ 2^-16 relative, dropped)
        __builtin_amdgcn_s_setprio(1);
#pragma unroll
        for (int nt = 0; nt < 4; ++nt)
            acc[nt] = __builtin_amdgcn_mfma_f32_16x16x32_bf16(ah, b[nt], acc[nt], 0, 0, 0);
#pragma unroll
        for (int nt = 0; nt < 4; ++nt)
            acc[nt] = __builtin_amdgcn_mfma_f32_16x16x32_bf16(al, b[nt], acc[nt], 0, 0, 0);
#pragma unroll
        for (int nt = 0; nt < 4; ++nt)
            acc[nt] = __builtin_amdgcn_mfma_f32_16x16x32_bf16(ah, b[4 + nt], acc[nt], 0, 0, 0);
        __builtin_amdgcn_s_setprio(0);
    };

    prep(0);
    __syncthreads();

    short8 ah, al;
    // phase: issue NEXT chunk's B reads (consumed next phase; counted lgkm
    // lets this phase's MFMA proceed) -> cvt + x refill -> mfma on current B
#define PH(cg, cl, BC, BN)                                           \
    {                                                                \
        if ((cl) + 1 < NCHP) dsB(BN, (cl) + 1);                      \
        SBAR();                                                      \
        cvt(x##_SLOT(cg), ah, al);                                   \
        if ((cg) + 3 < NCHB) x##_SLOT(cg) = ldx((cg) + 3);           \
        SBAR();                                                      \
        mfma12(ah, al, BC);                                          \
        SBAR();                                                      \
    }
#define x_SLOT0 x0
#define x_SLOT1 x1
#define x_SLOT2 x2

    // stage 0: global chunks 0..7 (ring slot = cg % 3)
    dsB(bA, 0);
    {
        // cg=0..7, local cl=0..7
        // slots: 0,1,2,0,1,2,0,1
        { if (1 < NCHP) dsB(bB, 1); SBAR(); cvt(x0, ah, al); x0 = ldx(3);  SBAR(); mfma12(ah, al, bA); SBAR(); }
        { if (2 < NCHP) dsB(bA, 2); SBAR(); cvt(x1, ah, al); x1 = ldx(4);  SBAR(); mfma12(ah, al, bB); SBAR(); }
        { if (3 < NCHP) dsB(bB, 3); SBAR(); cvt(x2, ah, al); x2 = ldx(5);  SBAR(); mfma12(ah, al, bA); SBAR(); }
        { if (4 < NCHP) dsB(bA, 4); SBAR(); cvt(x0, ah, al); x0 = ldx(6);  SBAR(); mfma12(ah, al, bB); SBAR(); }
        { if (5 < NCHP) dsB(bB, 5); SBAR(); cvt(x1, ah, al); x1 = ldx(7);  SBAR(); mfma12(ah, al, bA); SBAR(); }
        { if (6 < NCHP) dsB(bA, 6); SBAR(); cvt(x2, ah, al); x2 = ldx(8);  SBAR(); mfma12(ah, al, bB); SBAR(); }
        { if (7 < NCHP) dsB(bB, 7); SBAR(); cvt(x0, ah, al); x0 = ldx(9);  SBAR(); mfma12(ah, al, bA); SBAR(); }
        {                           SBAR(); cvt(x1, ah, al); x1 = ldx(10); SBAR(); mfma12(ah, al, bB); SBAR(); }
    }

    __syncthreads();          // all waves done reading stage-0 panel
    prep(1);
    __syncthreads();

    // stage 1: global chunks 8..15, local 0..7 (ring holds 8,9,10 in x2,x0,x1)
    dsB(bA, 0);
    {
        { if (1 < NCHP) dsB(bB, 1); SBAR(); cvt(x2, ah, al); x2 = ldx(11); SBAR(); mfma12(ah, al, bA); SBAR(); }
        { if (2 < NCHP) dsB(bA, 2); SBAR(); cvt(x0, ah, al); x0 = ldx(12); SBAR(); mfma12(ah, al, bB); SBAR(); }
        { if (3 < NCHP) dsB(bB, 3); SBAR(); cvt(x1, ah, al); x1 = ldx(13); SBAR(); mfma12(ah, al, bA); SBAR(); }
        { if (4 < NCHP) dsB(bA, 4); SBAR(); cvt(x2, ah, al); x2 = ldx(14); SBAR(); mfma12(ah, al, bB); SBAR(); }
        { if (5 < NCHP) dsB(bB, 5); SBAR(); cvt(x0, ah, al); x0 = ldx(15); SBAR(); mfma12(ah, al, bA); SBAR(); }
        { if (6 < NCHP) dsB(bA, 6); SBAR(); cvt(x1, ah, al);               SBAR(); mfma12(ah, al, bB); SBAR(); }
        { if (7 < NCHP) dsB(bB, 7); SBAR(); cvt(x2, ah, al);               SBAR(); mfma12(ah, al, bA); SBAR(); }
        {                           SBAR(); cvt(x0, ah, al);               SBAR(); mfma12(ah, al, bB); SBAR(); }
    }
#undef PH
#undef x_SLOT0
#undef x_SLOT1
#undef x_SLOT2

    // ---- direct partial write: wave owns its 16 tokens, no reduction ----
    // D layout (m89-verified): col = lane&15, row = grp*4 + reg
    float* pp = part + ((size_t)ks * TOKENS + t0) * NEXP;
#pragma unroll
    for (int nt = 0; nt < 4; ++nt)
#pragma unroll
        for (int r = 0; r < 4; ++r)
            pp[(grp * 4 + r) * NEXP + nt * 16 + row] = acc[nt][r];
}

// ---- finalize: sum 8 k-split partials, wave-per-token softmax + top-2 ----
__global__ __launch_bounds__(256)
void tg_final(const float* __restrict__ part,
              float* __restrict__ out_w, float* __restrict__ out_i) {
    const int lane = threadIdx.x & 63;
    const int wv   = threadIdx.x >> 6;
    const int t    = blockIdx.x * 4 + wv;        // one token per wave

    float s = 0.0f;
#pragma unroll
    for (int k = 0; k < KS; ++k)                 // coalesced 256-B reads
        s += part[((size_t)k * TOKENS + t) * NEXP + lane];

    // softmax over 64 lanes (butterfly: all lanes converge bit-identically)
    float m = s;
#pragma unroll
    for (int o = 32; o > 0; o >>= 1) m = fmaxf(m, __shfl_xor(m, o));
    float p = expf(s - m);
    float sum = p;
#pragma unroll
    for (int o = 32; o > 0; o >>= 1) sum += __shfl_xor(sum, o);
    const float prob = p / sum;

    // top-1: max value, tie -> lower index (jax top_k order)
    float v1 = prob; int i1 = lane;
#pragma unroll
    for (int o = 32; o > 0; o >>= 1) {
        float ov = __shfl_xor(v1, o); int oi = __shfl_xor(i1, o);
        if (ov > v1 || (ov == v1 && oi < i1)) { v1 = ov; i1 = oi; }
    }
    // top-2: mask winner (probs >= 0 > -1)
    float v2 = (lane == i1) ? -1.0f : prob; int i2 = lane;
#pragma unroll
    for (int o = 32; o > 0; o >>= 1) {
        float ov = __shfl_xor(v2, o); int oi = __shfl_xor(i2, o);
        if (ov > v2 || (ov == v2 && oi < i2)) { v2 = ov; i2 = oi; }
    }

    out_w[(size_t)t * NEXP + lane] = (lane == i1) ? v1 : (lane == i2) ? v2 : 0.0f;
    if (lane == 0) {
        out_i[(size_t)t * 2 + 0] = (float)i1;
        out_i[(size_t)t * 2 + 1] = (float)i2;
    }
}

extern "C" void kernel_launch(void* const* d_in, const int* in_sizes, int n_in,
                              void* d_out, int out_size, void* d_ws, size_t ws_size,
                              hipStream_t stream) {
    const float* x = (const float*)d_in[0];
    const float* W = (const float*)d_in[1];
    float* out_w = (float*)d_out;
    float* out_i = out_w + (size_t)TOKENS * NEXP;

    float* part = (float*)d_ws;   // KS * 8192 * 64 f32 = 16 MB

    tg_mfma <<<dim3((TOKENS / 128) * KS), dim3(512), 0, stream>>>(x, W, part);
    tg_final<<<dim3(TOKENS / 4), dim3(256), 0, stream>>>(part, out_w, out_i);
}

// Round 26
// 40.950 us; speedup vs baseline: 1.0460x; 1.0460x over previous
//
#include <hip/hip_runtime.h>
#include <math.h>

// TopKGate: logits = x @ W^T ; softmax ; top-2 ; scatter weights + indices(float).
// x: [8192,4096] f32, W: [64,4096] f32.
// d_out (f32 flat): weights [8192*64] then indices [8192*2] as floats.
//
// MFMA path: f32 as bf16 hi/lo split, 3 passes (hh+lh+hl; ll ~2^-16 dropped).
// FINAL (= Round-19/24, session best 40.9us). Measured design points:
//  - occupancy optimum: 16 waves/CU (8 -> 43.4, 16 -> 40.9, 20 starved -> 50)
//  - x-only vmem ring depth 4 (R17: time invariant to x residency; R25:
//    trading ring depth for B ping-pong regresses)
//  - 3-pass split mandatory (R23: 2-pass noise flips top-2 rankings)
//  - cross-XCD fused finalize impossible (R21 stale L2 / R22 agent-scope 185us)
// Structure: 512 thr (8 waves x 16 tok), launch_bounds(512,4), 64 KB B panel
// (K=256/stage, 2 stages, in-kernel prep), SBAR-fenced phases, partials +
// KS=8 wave-per-token butterfly finalize.

#define TOKENS 8192
#define DIM    4096
#define NEXP   64

#define KS     8                             // k-split across blocks
#define KSEG   (DIM / KS)                    // 512 k per block
#define NCHB   (KSEG / 32)                   // 16 chunks per block
#define PNK    256                           // k per panel stage
#define NCHP   (PNK / 32)                    // 8 chunks per stage

#define SBAR() __builtin_amdgcn_sched_barrier(0)

typedef __attribute__((ext_vector_type(8))) short  short8;
typedef __attribute__((ext_vector_type(4))) float  f32x4;
typedef __attribute__((ext_vector_type(8))) float  f32x8;

__device__ __forceinline__ void bf16split(float v, short& hi, short& lo) {
    unsigned u = __float_as_uint(v);
    hi = (short)(u >> 16);
    float r = v - __uint_as_float(u & 0xffff0000u);
    lo = (short)(__float_as_uint(r) >> 16);
}

// ---- main: 128 tokens/block (8 waves x 16), 2-stage 64 KB B panel ----
__global__ __launch_bounds__(512, 4)
void tg_mfma(const float* __restrict__ x, const float* __restrict__ W,
             float* __restrict__ part) {
    // B panel: [hi/lo][chunk][nt][lane] short8 = 64 KB
    __shared__ short8 Bls[2][NCHP][4][64];

    const int tid  = threadIdx.x;
    const int lane = tid & 63;
    const int wave = tid >> 6;                   // token sub-group 0..7
    const int tg   = blockIdx.x >> 3;            // token group 0..63
    const int ks   = blockIdx.x & 7;             // k split 0..7
    const int t0   = tg * 128 + wave * 16;
    const int row  = lane & 15;                  // A row (token) / D col tag
    const int grp  = lane >> 4;

    const float* xp = x + (size_t)(t0 + row) * DIM + ks * KSEG + grp * 8;
    auto ldx = [&](int c) {                      // c = global chunk 0..15
        return *reinterpret_cast<const f32x8*>(xp + c * 32);
    };

    // issue the x ring FIRST so it's deep in flight during stage-0 prep
    f32x8 x0 = ldx(0), x1 = ldx(1), x2 = ldx(2), x3 = ldx(3);

    // ---- B prep for one stage (validated mapping), 4 slots/thread ----
    auto prep = [&](int stage) {
        const int k0 = ks * KSEG + stage * PNK;
#pragma unroll
        for (int s4 = 0; s4 < 4; ++s4) {
            const int s   = s4 * 512 + tid;      // 0..2047
            const int c   = s >> 8;              // 0..7
            const int rem = s & 255;
            const int nt  = rem >> 6;
            const int ln  = rem & 63;
            const int e   = nt * 16 + (ln & 15);
            const int kb  = k0 + c * 32 + (ln >> 4) * 8;
            const f32x8 wv = *reinterpret_cast<const f32x8*>(W + (size_t)e * DIM + kb);
            short8 h, l;
#pragma unroll
            for (int j = 0; j < 8; ++j) {
                short hh, ll;
                bf16split(wv[j], hh, ll);
                h[j] = hh; l[j] = ll;
            }
            Bls[0][c][nt][ln] = h;
            Bls[1][c][nt][ln] = l;
        }
    };

    f32x4 acc[4];
#pragma unroll
    for (int nt = 0; nt < 4; ++nt) acc[nt] = (f32x4){0.f, 0.f, 0.f, 0.f};

    short8 b[8];
    auto dsB = [&](int c) {                      // 8 x ds_read_b128, conflict-free
#pragma unroll
        for (int nt = 0; nt < 4; ++nt) {
            b[nt]     = Bls[0][c][nt][lane];
            b[4 + nt] = Bls[1][c][nt][lane];
        }
    };
    auto cvt = [&](const f32x8& xv, short8& ah, short8& al) {
#pragma unroll
        for (int j = 0; j < 8; ++j) {
            short hh, ll;
            bf16split(xv[j], hh, ll);
            ah[j] = hh; al[j] = ll;
        }
    };
    auto mfma12 = [&](const short8& ah, const short8& al) {
        // 3-pass split: hh + lh + hl (ll ~ 2^-16 relative, dropped)
        __builtin_amdgcn_s_setprio(1);
#pragma unroll
        for (int nt = 0; nt < 4; ++nt)
            acc[nt] = __builtin_amdgcn_mfma_f32_16x16x32_bf16(ah, b[nt], acc[nt], 0, 0, 0);
#pragma unroll
        for (int nt = 0; nt < 4; ++nt)
            acc[nt] = __builtin_amdgcn_mfma_f32_16x16x32_bf16(al, b[nt], acc[nt], 0, 0, 0);
#pragma unroll
        for (int nt = 0; nt < 4; ++nt)
            acc[nt] = __builtin_amdgcn_mfma_f32_16x16x32_bf16(ah, b[4 + nt], acc[nt], 0, 0, 0);
        __builtin_amdgcn_s_setprio(0);
    };

    prep(0);
    __syncthreads();

    short8 ah, al;
    // phase: dsB issue -> cvt (covers LDS latency) + x refill -> mfma
#define PH(cg, cl, XV)                                               \
    {                                                                \
        dsB(cl);                                                     \
        SBAR();                                                      \
        cvt(XV, ah, al);                                             \
        if ((cg) + 4 < NCHB) XV = ldx((cg) + 4);                     \
        SBAR();                                                      \
        mfma12(ah, al);                                              \
        SBAR();                                                      \
    }

    // stage 0: global chunks 0..7
    PH(0, 0, x0)  PH(1, 1, x1)  PH(2, 2, x2)  PH(3, 3, x3)
    PH(4, 4, x0)  PH(5, 5, x1)  PH(6, 6, x2)  PH(7, 7, x3)

    __syncthreads();          // all waves done reading stage-0 panel
    prep(1);
    __syncthreads();

    // stage 1: global chunks 8..15 (x ring already holds 8..11)
    PH(8,  0, x0)  PH(9,  1, x1)  PH(10, 2, x2)  PH(11, 3, x3)
    PH(12, 4, x0)  PH(13, 5, x1)  PH(14, 6, x2)  PH(15, 7, x3)
#undef PH

    // ---- direct partial write: wave owns its 16 tokens, no reduction ----
    // D layout (m89-verified): col = lane&15, row = grp*4 + reg
    float* pp = part + ((size_t)ks * TOKENS + t0) * NEXP;
#pragma unroll
    for (int nt = 0; nt < 4; ++nt)
#pragma unroll
        for (int r = 0; r < 4; ++r)
            pp[(grp * 4 + r) * NEXP + nt * 16 + row] = acc[nt][r];
}

// ---- finalize: sum 8 k-split partials, wave-per-token softmax + top-2 ----
__global__ __launch_bounds__(256)
void tg_final(const float* __restrict__ part,
              float* __restrict__ out_w, float* __restrict__ out_i) {
    const int lane = threadIdx.x & 63;
    const int wv   = threadIdx.x >> 6;
    const int t    = blockIdx.x * 4 + wv;        // one token per wave

    float s = 0.0f;
#pragma unroll
    for (int k = 0; k < KS; ++k)                 // coalesced 256-B reads
        s += part[((size_t)k * TOKENS + t) * NEXP + lane];

    // softmax over 64 lanes (butterfly: all lanes converge bit-identically)
    float m = s;
#pragma unroll
    for (int o = 32; o > 0; o >>= 1) m = fmaxf(m, __shfl_xor(m, o));
    float p = expf(s - m);
    float sum = p;
#pragma unroll
    for (int o = 32; o > 0; o >>= 1) sum += __shfl_xor(sum, o);
    const float prob = p / sum;

    // top-1: max value, tie -> lower index (jax top_k order)
    float v1 = prob; int i1 = lane;
#pragma unroll
    for (int o = 32; o > 0; o >>= 1) {
        float ov = __shfl_xor(v1, o); int oi = __shfl_xor(i1, o);
        if (ov > v1 || (ov == v1 && oi < i1)) { v1 = ov; i1 = oi; }
    }
    // top-2: mask winner (probs >= 0 > -1)
    float v2 = (lane == i1) ? -1.0f : prob; int i2 = lane;
#pragma unroll
    for (int o = 32; o > 0; o >>= 1) {
        float ov = __shfl_xor(v2, o); int oi = __shfl_xor(i2, o);
        if (ov > v2 || (ov == v2 && oi < i2)) { v2 = ov; i2 = oi; }
    }

    out_w[(size_t)t * NEXP + lane] = (lane == i1) ? v1 : (lane == i2) ? v2 : 0.0f;
    if (lane == 0) {
        out_i[(size_t)t * 2 + 0] = (float)i1;
        out_i[(size_t)t * 2 + 1] = (float)i2;
    }
}

extern "C" void kernel_launch(void* const* d_in, const int* in_sizes, int n_in,
                              void* d_out, int out_size, void* d_ws, size_t ws_size,
                              hipStream_t stream) {
    const float* x = (const float*)d_in[0];
    const float* W = (const float*)d_in[1];
    float* out_w = (float*)d_out;
    float* out_i = out_w + (size_t)TOKENS * NEXP;

    float* part = (float*)d_ws;   // KS * 8192 * 64 f32 = 16 MB

    tg_mfma <<<dim3((TOKENS / 128) * KS), dim3(512), 0, stream>>>(x, W, part);
    tg_final<<<dim3(TOKENS / 4), dim3(256), 0, stream>>>(part, out_w, out_i);
}

// Round 27
// 39.843 us; speedup vs baseline: 1.0751x; 1.0278x over previous
//
#include <hip/hip_runtime.h>
#include <math.h>

// TopKGate: logits = x @ W^T ; softmax ; top-2 ; scatter weights + indices(float).
// x: [8192,4096] f32, W: [64,4096] f32.
// d_out (f32 flat): weights [8192*64] then indices [8192*2] as floats.
//
// MFMA path: f32 as bf16 hi/lo split, 3 passes (hh+lh+hl; ll ~2^-16 dropped).
// Round-27 = Round-24 (40.9us best) + WAVE SKEW: each wave processes the
// panel's 8 chunks rotated by its wave id (phase i -> chunk (i+wave)&7), so
// the block's 8 waves occupy 8 DIFFERENT phase types at any instant instead
// of bursting dsB/cvt/mfma in lockstep after the barrier. Totals unchanged
// (same loads/LDS reads/MFMAs/ring depth); per-wave order fixed per thread
// -> deterministic. Targets the convoy signature: all pipes <10% busy, time
// invariant to x residency (R17), insensitive to phase granularity (R18).

#define TOKENS 8192
#define DIM    4096
#define NEXP   64

#define KS     8                             // k-split across blocks
#define KSEG   (DIM / KS)                    // 512 k per block
#define NCHB   (KSEG / 32)                   // 16 chunks per block
#define PNK    256                           // k per panel stage
#define NCHP   (PNK / 32)                    // 8 chunks per stage

#define SBAR() __builtin_amdgcn_sched_barrier(0)

typedef __attribute__((ext_vector_type(8))) short  short8;
typedef __attribute__((ext_vector_type(4))) float  f32x4;
typedef __attribute__((ext_vector_type(8))) float  f32x8;

__device__ __forceinline__ void bf16split(float v, short& hi, short& lo) {
    unsigned u = __float_as_uint(v);
    hi = (short)(u >> 16);
    float r = v - __uint_as_float(u & 0xffff0000u);
    lo = (short)(__float_as_uint(r) >> 16);
}

// ---- main: 128 tokens/block (8 waves x 16), 2-stage 64 KB B panel ----
__global__ __launch_bounds__(512, 4)
void tg_mfma(const float* __restrict__ x, const float* __restrict__ W,
             float* __restrict__ part) {
    // B panel: [hi/lo][chunk][nt][lane] short8 = 64 KB
    __shared__ short8 Bls[2][NCHP][4][64];

    const int tid  = threadIdx.x;
    const int lane = tid & 63;
    const int wave = tid >> 6;                   // token sub-group 0..7
    const int tg   = blockIdx.x >> 3;            // token group 0..63
    const int ks   = blockIdx.x & 7;             // k split 0..7
    const int t0   = tg * 128 + wave * 16;
    const int row  = lane & 15;                  // A row (token) / D col tag
    const int grp  = lane >> 4;
    const int rot  = wave;                       // per-wave chunk rotation

    const float* xp = x + (size_t)(t0 + row) * DIM + ks * KSEG + grp * 8;
    auto ldx = [&](int c) {                      // c = global chunk 0..15
        return *reinterpret_cast<const f32x8*>(xp + c * 32);
    };
    // rotated global chunk sequence: phase i -> stage(i)*8 + ((i+rot)&7)
    auto seq = [&](int i) { return ((i >> 3) << 3) + ((i + rot) & 7); };

    // issue the x ring FIRST so it's deep in flight during stage-0 prep
    f32x8 x0 = ldx(seq(0)), x1 = ldx(seq(1)),
          x2 = ldx(seq(2)), x3 = ldx(seq(3));

    // ---- B prep for one stage (validated mapping), 4 slots/thread ----
    auto prep = [&](int stage) {
        const int k0 = ks * KSEG + stage * PNK;
#pragma unroll
        for (int s4 = 0; s4 < 4; ++s4) {
            const int s   = s4 * 512 + tid;      // 0..2047
            const int c   = s >> 8;              // 0..7
            const int rem = s & 255;
            const int nt  = rem >> 6;
            const int ln  = rem & 63;
            const int e   = nt * 16 + (ln & 15);
            const int kb  = k0 + c * 32 + (ln >> 4) * 8;
            const f32x8 wv = *reinterpret_cast<const f32x8*>(W + (size_t)e * DIM + kb);
            short8 h, l;
#pragma unroll
            for (int j = 0; j < 8; ++j) {
                short hh, ll;
                bf16split(wv[j], hh, ll);
                h[j] = hh; l[j] = ll;
            }
            Bls[0][c][nt][ln] = h;
            Bls[1][c][nt][ln] = l;
        }
    };

    f32x4 acc[4];
#pragma unroll
    for (int nt = 0; nt < 4; ++nt) acc[nt] = (f32x4){0.f, 0.f, 0.f, 0.f};

    short8 b[8];
    auto dsB = [&](int c) {                      // 8 x ds_read_b128, conflict-free
#pragma unroll
        for (int nt = 0; nt < 4; ++nt) {
            b[nt]     = Bls[0][c][nt][lane];
            b[4 + nt] = Bls[1][c][nt][lane];
        }
    };
    auto cvt = [&](const f32x8& xv, short8& ah, short8& al) {
#pragma unroll
        for (int j = 0; j < 8; ++j) {
            short hh, ll;
            bf16split(xv[j], hh, ll);
            ah[j] = hh; al[j] = ll;
        }
    };
    auto mfma12 = [&](const short8& ah, const short8& al) {
        // 3-pass split: hh + lh + hl (ll ~ 2^-16 relative, dropped)
        __builtin_amdgcn_s_setprio(1);
#pragma unroll
        for (int nt = 0; nt < 4; ++nt)
            acc[nt] = __builtin_amdgcn_mfma_f32_16x16x32_bf16(ah, b[nt], acc[nt], 0, 0, 0);
#pragma unroll
        for (int nt = 0; nt < 4; ++nt)
            acc[nt] = __builtin_amdgcn_mfma_f32_16x16x32_bf16(al, b[nt], acc[nt], 0, 0, 0);
#pragma unroll
        for (int nt = 0; nt < 4; ++nt)
            acc[nt] = __builtin_amdgcn_mfma_f32_16x16x32_bf16(ah, b[4 + nt], acc[nt], 0, 0, 0);
        __builtin_amdgcn_s_setprio(0);
    };

    prep(0);
    __syncthreads();

    short8 ah, al;
    // phase i: dsB rotated chunk -> cvt (covers LDS latency) + x refill -> mfma
#define PH(i, XV)                                                    \
    {                                                                \
        dsB((i + rot) & 7);                                          \
        SBAR();                                                      \
        cvt(XV, ah, al);                                             \
        if ((i) + 4 < NCHB) XV = ldx(seq((i) + 4));                  \
        SBAR();                                                      \
        mfma12(ah, al);                                              \
        SBAR();                                                      \
    }

    // stage 0: phases 0..7 (local chunks rotated per wave)
    PH(0, x0)  PH(1, x1)  PH(2, x2)  PH(3, x3)
    PH(4, x0)  PH(5, x1)  PH(6, x2)  PH(7, x3)

    __syncthreads();          // all waves done reading stage-0 panel
    prep(1);
    __syncthreads();

    // stage 1: phases 8..15 (ring already holds seq(8..11))
    PH(8,  x0)  PH(9,  x1)  PH(10, x2)  PH(11, x3)
    PH(12, x0)  PH(13, x1)  PH(14, x2)  PH(15, x3)
#undef PH

    // ---- direct partial write: wave owns its 16 tokens, no reduction ----
    // D layout (m89-verified): col = lane&15, row = grp*4 + reg
    float* pp = part + ((size_t)ks * TOKENS + t0) * NEXP;
#pragma unroll
    for (int nt = 0; nt < 4; ++nt)
#pragma unroll
        for (int r = 0; r < 4; ++r)
            pp[(grp * 4 + r) * NEXP + nt * 16 + row] = acc[nt][r];
}

// ---- finalize: sum 8 k-split partials, wave-per-token softmax + top-2 ----
__global__ __launch_bounds__(256)
void tg_final(const float* __restrict__ part,
              float* __restrict__ out_w, float* __restrict__ out_i) {
    const int lane = threadIdx.x & 63;
    const int wv   = threadIdx.x >> 6;
    const int t    = blockIdx.x * 4 + wv;        // one token per wave

    float s = 0.0f;
#pragma unroll
    for (int k = 0; k < KS; ++k)                 // coalesced 256-B reads
        s += part[((size_t)k * TOKENS + t) * NEXP + lane];

    // softmax over 64 lanes (butterfly: all lanes converge bit-identically)
    float m = s;
#pragma unroll
    for (int o = 32; o > 0; o >>= 1) m = fmaxf(m, __shfl_xor(m, o));
    float p = expf(s - m);
    float sum = p;
#pragma unroll
    for (int o = 32; o > 0; o >>= 1) sum += __shfl_xor(sum, o);
    const float prob = p / sum;

    // top-1: max value, tie -> lower index (jax top_k order)
    float v1 = prob; int i1 = lane;
#pragma unroll
    for (int o = 32; o > 0; o >>= 1) {
        float ov = __shfl_xor(v1, o); int oi = __shfl_xor(i1, o);
        if (ov > v1 || (ov == v1 && oi < i1)) { v1 = ov; i1 = oi; }
    }
    // top-2: mask winner (probs >= 0 > -1)
    float v2 = (lane == i1) ? -1.0f : prob; int i2 = lane;
#pragma unroll
    for (int o = 32; o > 0; o >>= 1) {
        float ov = __shfl_xor(v2, o); int oi = __shfl_xor(i2, o);
        if (ov > v2 || (ov == v2 && oi < i2)) { v2 = ov; i2 = oi; }
    }

    out_w[(size_t)t * NEXP + lane] = (lane == i1) ? v1 : (lane == i2) ? v2 : 0.0f;
    if (lane == 0) {
        out_i[(size_t)t * 2 + 0] = (float)i1;
        out_i[(size_t)t * 2 + 1] = (float)i2;
    }
}

extern "C" void kernel_launch(void* const* d_in, const int* in_sizes, int n_in,
                              void* d_out, int out_size, void* d_ws, size_t ws_size,
                              hipStream_t stream) {
    const float* x = (const float*)d_in[0];
    const float* W = (const float*)d_in[1];
    float* out_w = (float*)d_out;
    float* out_i = out_w + (size_t)TOKENS * NEXP;

    float* part = (float*)d_ws;   // KS * 8192 * 64 f32 = 16 MB

    tg_mfma <<<dim3((TOKENS / 128) * KS), dim3(512), 0, stream>>>(x, W, part);
    tg_final<<<dim3(TOKENS / 4), dim3(256), 0, stream>>>(part, out_w, out_i);
}